// Round 1
// baseline (315.468 us; speedup 1.0000x reference)
//
#include <hip/hip_runtime.h>
#include <math.h>

// Problem constants (from reference):
// B=64, MAX_H=64, MAX_W=32, D=512, S=8, HID=64
#define NB    64
#define MAXH  64
#define MAXW  32
#define DCH   512
#define SS    8
#define HID   64

#define QTOTAL ((size_t)NB * MAXH * MAXW * DCH)   // 67,108,864 floats

__device__ __forceinline__ float gelu_exact(float x) {
    // jax.nn.gelu(approximate=False): x * 0.5 * (1 + erf(x/sqrt(2)))
    return 0.5f * x * (1.0f + erff(x * 0.70710678118654752440f));
}

__global__ __launch_bounds__(256) void hgqg_kernel(
    const float* __restrict__ canonical,  // (8,8,512)
    const float* __restrict__ w1,         // (2,64)
    const float* __restrict__ b1,         // (64,)
    const float* __restrict__ w2,         // (64,512)
    const float* __restrict__ b2,         // (512,)
    const int*   __restrict__ hlist,      // (64,)
    const int*   __restrict__ wlist,      // (64,)
    float* __restrict__ out)              // queries flat, then mask flat
{
    const int blk = blockIdx.x;       // b*64 + i
    const int b   = blk >> 6;
    const int i   = blk & 63;
    const int t   = threadIdx.x;

    int H = hlist[b]; H = min(max(H, 1), MAXH);
    int W = wlist[b]; W = min(max(W, 1), MAXW);

    float* qrow = out + (size_t)blk * (MAXW * DCH);
    float* mrow = out + QTOTAL + (size_t)blk * MAXW;

    const bool row_active = (i < H);

    // mask row: bool -> 0.0/1.0 floats
    if (t < MAXW) {
        mrow[t] = (row_active && t < W) ? 1.0f : 0.0f;
    }

    if (!row_active) {
        // entire row of queries is zero: 32*512 = 16384 floats = 4096 float4
        float4 z = make_float4(0.f, 0.f, 0.f, 0.f);
        float4* q4 = (float4*)qrow;
        #pragma unroll
        for (int r = 0; r < 16; ++r) q4[t + r * 256] = z;
        return;
    }

    // ---- per-row scalars (uniform across block) ----
    const float u  = (H > 1) ? (float)i / (float)(H - 1) : 0.0f;
    const float sy = fminf(fmaxf(u * 7.0f, 0.0f), 7.0f);
    const int   y0 = (int)floorf(sy);
    const int   y1 = min(y0 + 1, SS - 1);
    const float wy = sy - (float)y0;
    const float winv = (W > 1) ? 1.0f / (float)(W - 1) : 0.0f;

    // ---- cooperative h = gelu(coords @ w1 + b1) for all 32 j's ----
    __shared__ float hsh[MAXW][HID];   // 8 KB
    {
        const int j  = t >> 3;             // 0..31
        const int k0 = (t & 7) * 8;        // 0..56
        const float v = (float)j * winv;   // matches where(W>1, j/(W-1), 0)
        #pragma unroll
        for (int kk = 0; kk < 8; ++kk) {
            const int k = k0 + kk;
            const float x = u * w1[k] + v * w1[HID + k] + b1[k];
            hsh[j][k] = gelu_exact(x);
        }
    }
    __syncthreads();

    // ---- main: each thread owns 4 channels for 16 interleaved j's ----
    const int cid = t & 127;          // channel/4 index: 0..127
    const int jg  = t >> 7;           // 0 or 1; j = jg, jg+2, ..., jg+30
    const float4* can4 = (const float4*)canonical;   // idx (y*8+x)*128 + cid
    const float4* w2v4 = (const float4*)w2;          // idx k*128 + cid
    const float4  bb2  = ((const float4*)b2)[cid];

    float4 acc[16];

    // init with bilinear + b2 (active j) or zero
    #pragma unroll
    for (int s = 0; s < 16; ++s) {
        const int j = jg + 2 * s;
        if (j < W) {
            const float vv  = (float)j * winv;
            const float sx  = fminf(fmaxf(vv * 7.0f, 0.0f), 7.0f);
            const float fx0 = floorf(sx);
            const int   x0  = (int)fx0;
            const int   x1  = min(x0 + 1, SS - 1);
            const float wx  = sx - fx0;
            const float4 q00 = can4[(y0 * SS + x0) * 128 + cid];
            const float4 q01 = can4[(y0 * SS + x1) * 128 + cid];
            const float4 q10 = can4[(y1 * SS + x0) * 128 + cid];
            const float4 q11 = can4[(y1 * SS + x1) * 128 + cid];
            float4 t0, t1, bil;
            t0.x = q00.x + wx * (q01.x - q00.x);
            t0.y = q00.y + wx * (q01.y - q00.y);
            t0.z = q00.z + wx * (q01.z - q00.z);
            t0.w = q00.w + wx * (q01.w - q00.w);
            t1.x = q10.x + wx * (q11.x - q10.x);
            t1.y = q10.y + wx * (q11.y - q10.y);
            t1.z = q10.z + wx * (q11.z - q10.z);
            t1.w = q10.w + wx * (q11.w - q10.w);
            bil.x = t0.x + wy * (t1.x - t0.x);
            bil.y = t0.y + wy * (t1.y - t0.y);
            bil.z = t0.z + wy * (t1.z - t0.z);
            bil.w = t0.w + wy * (t1.w - t0.w);
            acc[s].x = bil.x + bb2.x;
            acc[s].y = bil.y + bb2.y;
            acc[s].z = bil.z + bb2.z;
            acc[s].w = bil.w + bb2.w;
        } else {
            acc[s] = make_float4(0.f, 0.f, 0.f, 0.f);
        }
    }

    // GEMV: acc[j][c..c+3] += sum_k h[j][k] * w2[k][c..c+3]
    // k-blocked by 4 so each w2 element is loaded exactly once per thread.
    for (int kb = 0; kb < HID; kb += 4) {
        const float4 wa = w2v4[(kb + 0) * 128 + cid];
        const float4 wb = w2v4[(kb + 1) * 128 + cid];
        const float4 wc = w2v4[(kb + 2) * 128 + cid];
        const float4 wd = w2v4[(kb + 3) * 128 + cid];
        #pragma unroll
        for (int s = 0; s < 16; ++s) {
            const int j = jg + 2 * s;
            if (j < W) {
                const float4 h4 = *(const float4*)&hsh[j][kb];  // wave-uniform addr -> broadcast
                acc[s].x += h4.x * wa.x + h4.y * wb.x + h4.z * wc.x + h4.w * wd.x;
                acc[s].y += h4.x * wa.y + h4.y * wb.y + h4.z * wc.y + h4.w * wd.y;
                acc[s].z += h4.x * wa.z + h4.y * wb.z + h4.z * wc.z + h4.w * wd.z;
                acc[s].w += h4.x * wa.w + h4.y * wb.w + h4.z * wc.w + h4.w * wd.w;
            }
        }
    }

    // store all 16 slots (zeros for masked j)
    float4* q4 = (float4*)qrow;
    #pragma unroll
    for (int s = 0; s < 16; ++s) {
        const int j = jg + 2 * s;
        q4[j * 128 + cid] = acc[s];
    }
}

extern "C" void kernel_launch(void* const* d_in, const int* in_sizes, int n_in,
                              void* d_out, int out_size, void* d_ws, size_t ws_size,
                              hipStream_t stream) {
    // setup_inputs order:
    // 0 canonical (8,8,512) f32 | 1 w1 (2,64) f32 | 2 b1 (64,) f32
    // 3 w2 (64,512) f32 | 4 b2 (512,) f32 | 5 batch_size (1,) i32
    // 6 target_h_list (64,) i32 | 7 target_w_list (64,) i32
    // 8 max_h (1,) i32 | 9 max_w (1,) i32
    const float* canonical = (const float*)d_in[0];
    const float* w1        = (const float*)d_in[1];
    const float* b1        = (const float*)d_in[2];
    const float* w2        = (const float*)d_in[3];
    const float* b2        = (const float*)d_in[4];
    const int*   hlist     = (const int*)d_in[6];
    const int*   wlist     = (const int*)d_in[7];
    float* out = (float*)d_out;

    hgqg_kernel<<<NB * MAXH, 256, 0, stream>>>(
        canonical, w1, b1, w2, b2, hlist, wlist, out);
}